// Round 14
// baseline (400.479 us; speedup 1.0000x reference)
//
#include <hip/hip_runtime.h>
#include <hip/hip_bf16.h>
#include <math.h>

#define NN 50000
#define NP 50048            // NN padded to 64-row tiles
#define NE 800000
#define ET (NE + NN)
#define DF 128
#define NH 4
#define HD 512
#define BN_EPS 1e-5f

typedef __hip_bfloat16 bf16;
typedef __attribute__((ext_vector_type(8))) short bf16x8;
typedef __attribute__((ext_vector_type(4))) float f32x4;

// ---------- input conversions ----------
__global__ __launch_bounds__(256) void cvt_x_bf16(const float* __restrict__ in, bf16* __restrict__ out) {
    int i = blockIdx.x * 256 + threadIdx.x;            // 4 elements per thread
    if (i >= NN * DF / 4) return;
    float4 v = reinterpret_cast<const float4*>(in)[i];
    union { bf16 b[4]; short4 s; } u;
    u.b[0] = __float2bfloat16(v.x); u.b[1] = __float2bfloat16(v.y);
    u.b[2] = __float2bfloat16(v.z); u.b[3] = __float2bfloat16(v.w);
    reinterpret_cast<short4*>(out)[i] = u.s;
}

// wsd[layer][o][d] = sum_c W[d, h*128+c] * att[h][c],  o=h (src, 0..3) or 4+h (dst)
__global__ __launch_bounds__(256) void make_wsd(const float* __restrict__ W1, const float* __restrict__ as1,
                                                const float* __restrict__ ad1,
                                                const float* __restrict__ W2, const float* __restrict__ as2,
                                                const float* __restrict__ ad2,
                                                float* __restrict__ wsd) {
    int t = blockIdx.x * 256 + threadIdx.x;   // 0..2047
    if (t >= 2048) return;
    int layer = t >> 10;
    int o = (t >> 7) & 7;
    int d = t & 127;
    int h = o & 3;
    const float* W  = layer ? W2 : W1;
    const float* av = layer ? (o < 4 ? as2 : ad2) : (o < 4 ? as1 : ad1);
    const float* wrow = W + d * HD + h * DF;
    const float* arow = av + h * DF;
    float sum = 0.f;
    for (int c = 0; c < DF; ++c) sum += wrow[c] * arow[c];
    wsd[layer * 1024 + o * DF + d] = sum;
}

// Bt2[layer][c][h*128+d] = 0.25 * W[d][h*128+c]   (stacked, transposed, head-mean folded)
__global__ __launch_bounds__(256) void cvt_bt2(const float* __restrict__ W1, const float* __restrict__ W2,
                                               bf16* __restrict__ B1, bf16* __restrict__ B2) {
    int i = blockIdx.x * 256 + threadIdx.x;   // 0..131071
    if (i >= 2 * DF * HD) return;
    int layer = i >> 16;
    int ii = i & 65535;
    int c = ii >> 9, k = ii & 511;
    int h = k >> 7, d = k & 127;
    const float* W = layer ? W2 : W1;
    bf16* B = layer ? B2 : B1;
    B[ii] = __float2bfloat16(0.25f * W[d * HD + h * DF + c]);
}

// ---------- per-node scores from x (+ stats zeroing in block 0) ----------
__global__ __launch_bounds__(256) void xscore(const bf16* __restrict__ X,
                                              const float* __restrict__ wsd,   // [8][128]
                                              float* __restrict__ a_src,
                                              float* __restrict__ a_dst,
                                              float* __restrict__ stats) {
    if (blockIdx.x == 0 && threadIdx.x < 64)
        reinterpret_cast<float4*>(stats)[threadIdx.x] = make_float4(0.f, 0.f, 0.f, 0.f);
    __shared__ float w[8][DF];
    reinterpret_cast<float4*>(&w[0][0])[threadIdx.x] = reinterpret_cast<const float4*>(wsd)[threadIdx.x];
    __syncthreads();
    const int n = blockIdx.x * 4 + (threadIdx.x >> 6);
    const int l = threadIdx.x & 63;          // lane owns features 2l, 2l+1
    unsigned xv = reinterpret_cast<const unsigned*>(X)[n * 64 + l];
    float x0 = __uint_as_float(xv << 16);
    float x1 = __uint_as_float(xv & 0xffff0000u);
    float v[8];
    #pragma unroll
    for (int o = 0; o < 8; ++o)
        v[o] = x0 * w[o][2 * l] + x1 * w[o][2 * l + 1];
    #pragma unroll
    for (int off = 1; off < 64; off <<= 1) {
        #pragma unroll
        for (int o = 0; o < 8; ++o) v[o] += __shfl_xor(v[o], off);
    }
    if (l == 0) {
        reinterpret_cast<float4*>(a_src)[n] = make_float4(v[0], v[1], v[2], v[3]);
        reinterpret_cast<float4*>(a_dst)[n] = make_float4(v[4], v[5], v[6], v[7]);
    }
}

// ---------- CSR build: single atomic pass (rank trick) ----------
__global__ __launch_bounds__(256) void count_rank(const int* __restrict__ ei, int* __restrict__ counts,
                                                  int* __restrict__ rank) {
    int e = (blockIdx.x * 256 + threadIdx.x) * 2;
    if (e >= ET) return;
    int d0, d1;
    if (e + 1 < NE) {
        int2 dd = *reinterpret_cast<const int2*>(ei + NE + e);
        d0 = dd.x; d1 = dd.y;
    } else {
        d0 = (e < NE) ? ei[NE + e] : (e - NE);
        d1 = (e + 1 < NE) ? ei[NE + e + 1] : (e + 1 - NE);
    }
    rank[e]     = atomicAdd(&counts[d0 << 4], 1);
    rank[e + 1] = atomicAdd(&counts[d1 << 4], 1);
}

__global__ __launch_bounds__(256) void scan1(const int* __restrict__ counts, int* __restrict__ bsum) {
    __shared__ int sd[256];
    int i = blockIdx.x * 256 + threadIdx.x;
    sd[threadIdx.x] = (i < NN) ? counts[i << 4] : 0;
    __syncthreads();
    for (int s = 128; s > 0; s >>= 1) {
        if (threadIdx.x < s) sd[threadIdx.x] += sd[threadIdx.x + s];
        __syncthreads();
    }
    if (threadIdx.x == 0) bsum[blockIdx.x] = sd[0];
}

// parallel exclusive scan over <=256 block sums (Hillis-Steele)
__global__ __launch_bounds__(256) void scan2(int* __restrict__ bsum, int nb) {
    __shared__ int sd[256];
    int i = threadIdx.x;
    int v = (i < nb) ? bsum[i] : 0;
    sd[i] = v;
    __syncthreads();
    for (int s = 1; s < 256; s <<= 1) {
        int t = sd[i];
        int u = (i >= s) ? sd[i - s] : 0;
        __syncthreads();
        sd[i] = t + u;
        __syncthreads();
    }
    if (i < nb) bsum[i] = sd[i] - v;
}

__global__ __launch_bounds__(256) void scan3(const int* __restrict__ counts, const int* __restrict__ bsum,
                                             int* __restrict__ row_ptr) {
    __shared__ int sd[256];
    int i = blockIdx.x * 256 + threadIdx.x;
    int v = (i < NN) ? counts[i << 4] : 0;
    sd[threadIdx.x] = v;
    __syncthreads();
    for (int s = 1; s < 256; s <<= 1) {
        int t = sd[threadIdx.x];
        int u = (threadIdx.x >= s) ? sd[threadIdx.x - s] : 0;
        __syncthreads();
        sd[threadIdx.x] = t + u;
        __syncthreads();
    }
    int excl = sd[threadIdx.x] - v + bsum[blockIdx.x];
    if (i < NN) row_ptr[i] = excl;
    if (i == 0) row_ptr[NN] = ET;
}

// non-atomic scatter: col[row_ptr[d] + rank[e]] = src(e)
__global__ __launch_bounds__(256) void fill_scatter(const int* __restrict__ ei, const int* __restrict__ rank,
                                                    const int* __restrict__ row_ptr, int* __restrict__ col) {
    int e = (blockIdx.x * 256 + threadIdx.x) * 2;
    if (e >= ET) return;
    int s0, d0, s1, d1;
    if (e + 1 < NE) {
        int2 ss = *reinterpret_cast<const int2*>(ei + e);
        int2 dd = *reinterpret_cast<const int2*>(ei + NE + e);
        s0 = ss.x; s1 = ss.y; d0 = dd.x; d1 = dd.y;
    } else {
        if (e < NE) { s0 = ei[e]; d0 = ei[NE + e]; } else { s0 = d0 = e - NE; }
        if (e + 1 < NE) { s1 = ei[e + 1]; d1 = ei[NE + e + 1]; } else { s1 = d1 = e + 1 - NE; }
    }
    int2 rk = *reinterpret_cast<const int2*>(rank + e);
    col[row_ptr[d0] + rk.x] = s0;
    col[row_ptr[d1] + rk.y] = s1;
}

// ---------- fused softmax + gather (one wave per node, LDS alpha staging) ----------
// Phase A (per 64-edge chunk): lane j computes edge j's softmax p (flash-style running
// m/s, shfl reduces), stages (col, p[4]) in per-wave LDS.  Phase B: 16-lane group g
// gathers edge ee+g's x row as uint4 (4 edges per VMEM instr), FMA into acc[4][8].
// No barriers: LDS regions are per-wave; intra-wave LDS ordering only.
__global__ __launch_bounds__(256) void agg_fused(const bf16* __restrict__ X,
                                                 const float* __restrict__ a_src,
                                                 const float* __restrict__ a_dst,
                                                 const int* __restrict__ row_ptr,
                                                 const int* __restrict__ col,
                                                 bf16* __restrict__ aggX) {
    __shared__ __align__(16) float4 pal[4][64];
    __shared__ int pcol[4][64];
    const int w = threadIdx.x >> 6;
    const int n = blockIdx.x * 4 + w;
    const int l = threadIdx.x & 63;
    const int g = l >> 4;                // gather group: edge slot
    const int q = l & 15;                // uint4 index within the 256B row
    const int start = row_ptr[n], end = row_ptr[n + 1];
    const float4 ad4 = reinterpret_cast<const float4*>(a_dst)[n];
    const float4* __restrict__ as4 = reinterpret_cast<const float4*>(a_src);
    const uint4* __restrict__ X16 = reinterpret_cast<const uint4*>(X);   // 16 per row
    float m[4] = {-1e30f, -1e30f, -1e30f, -1e30f};
    float s[4] = {0.f, 0.f, 0.f, 0.f};
    float acc[4][8] = {};
    for (int base = start; base < end; base += 64) {
        const int j = base + l;
        const bool valid = j < end;
        const int cj = valid ? col[j] : 0;
        float lv[4] = {-1e30f, -1e30f, -1e30f, -1e30f};
        if (valid) {
            float4 a = as4[cj];
            lv[0] = a.x + ad4.x; lv[1] = a.y + ad4.y; lv[2] = a.z + ad4.z; lv[3] = a.w + ad4.w;
            #pragma unroll
            for (int h = 0; h < 4; ++h) lv[h] = lv[h] > 0.f ? lv[h] : 0.2f * lv[h];
        }
        float cm[4];
        #pragma unroll
        for (int h = 0; h < 4; ++h) cm[h] = lv[h];
        #pragma unroll
        for (int off = 1; off < 64; off <<= 1) {
            #pragma unroll
            for (int h = 0; h < 4; ++h) cm[h] = fmaxf(cm[h], __shfl_xor(cm[h], off));
        }
        float p[4], ps[4];
        #pragma unroll
        for (int h = 0; h < 4; ++h) {
            float nm = fmaxf(m[h], cm[h]);
            float sc = __expf(m[h] - nm);            // first chunk: 0
            p[h] = valid ? __expf(lv[h] - nm) : 0.f;
            s[h] *= sc;
            #pragma unroll
            for (int f = 0; f < 8; ++f) acc[h][f] *= sc;
            m[h] = nm;
            ps[h] = p[h];
        }
        #pragma unroll
        for (int off = 1; off < 64; off <<= 1) {
            #pragma unroll
            for (int h = 0; h < 4; ++h) ps[h] += __shfl_xor(ps[h], off);
        }
        #pragma unroll
        for (int h = 0; h < 4; ++h) s[h] += ps[h];
        pal[w][l] = make_float4(p[0], p[1], p[2], p[3]);
        pcol[w][l] = cj;                             // invalid lanes: cj=0, p=0
        __builtin_amdgcn_wave_barrier();             // order LDS writes before reads
        const int cnt = min(64, end - base);
        for (int ee = 0; ee < cnt; ee += 4) {        // groups read ee+g <= 63 (p=0 pads)
            int cc = pcol[w][ee + g];
            float4 pa = pal[w][ee + g];
            uint4 xv = X16[(size_t)cc * 16 + q];
            float xf[8];
            xf[0] = __uint_as_float(xv.x << 16); xf[1] = __uint_as_float(xv.x & 0xffff0000u);
            xf[2] = __uint_as_float(xv.y << 16); xf[3] = __uint_as_float(xv.y & 0xffff0000u);
            xf[4] = __uint_as_float(xv.z << 16); xf[5] = __uint_as_float(xv.z & 0xffff0000u);
            xf[6] = __uint_as_float(xv.w << 16); xf[7] = __uint_as_float(xv.w & 0xffff0000u);
            #pragma unroll
            for (int f = 0; f < 8; ++f) {
                acc[0][f] += pa.x * xf[f];
                acc[1][f] += pa.y * xf[f];
                acc[2][f] += pa.z * xf[f];
                acc[3][f] += pa.w * xf[f];
            }
        }
        __builtin_amdgcn_wave_barrier();             // reads done before next chunk's writes
    }
    // merge the 4 gather groups
    #pragma unroll
    for (int h = 0; h < 4; ++h)
        #pragma unroll
        for (int f = 0; f < 8; ++f) {
            acc[h][f] += __shfl_xor(acc[h][f], 16);
            acc[h][f] += __shfl_xor(acc[h][f], 32);
        }
    if (l < 16) {
        uint4* outp = reinterpret_cast<uint4*>(aggX) + (size_t)n * 64;   // 64 uint4 per row
        #pragma unroll
        for (int h = 0; h < 4; ++h) {
            float inv = 1.f / s[h];
            uint4 wv;
            unsigned short* wb = reinterpret_cast<unsigned short*>(&wv);
            #pragma unroll
            for (int f = 0; f < 8; ++f) {
                union { bf16 b; unsigned short u; } t;
                t.b = __float2bfloat16(acc[h][f] * inv);
                wb[f] = t.u;
            }
            outp[h * 16 + q] = wv;
        }
    }
}

// ---------- MFMA GEMM: agg[M,128](bf16) = A[M,512](bf16) @ Bt[128,512]^T + bias ----------
// B LDS-resident in two 64KB K-phases; A streamed global->VGPR (no barriers in main loop).
__global__ __launch_bounds__(256) void gemm_out(const bf16* __restrict__ A,
                                                const bf16* __restrict__ Bt,
                                                const float* __restrict__ bias,
                                                bf16* __restrict__ outb,
                                                float* __restrict__ stats, int M) {
    __shared__ __align__(16) char Bs[65536];      // [128 cols][512B K-phase], XOR-swizzled
    __shared__ float ssum[128], ssq[128];
    const int tid = threadIdx.x;
    if (tid < 128) { ssum[tid] = 0.f; ssq[tid] = 0.f; }
    const int m0 = blockIdx.x * 64;
    const char* Ab = (const char*)A + (size_t)m0 * 1024;     // row stride 512*2 B
    const char* Bb = (const char*)Bt;
    auto stageB = [&](int ph) {
        #pragma unroll
        for (int i = 0; i < 16; ++i) {
            int d = (tid + i * 256) * 16;        // 0..65535
            int c = d >> 9;                      // col 0..127
            int kb = d & 511;
            int src = c * 1024 + ph * 512 + (kb ^ ((c & 7) << 4));
            __builtin_amdgcn_global_load_lds(
                (const __attribute__((address_space(1))) void*)(Bb + src),
                (__attribute__((address_space(3))) void*)(Bs + d), 16, 0, 0);
        }
    };
    const int lane = tid & 63;
    const int wave = tid >> 6;
    const int wm = (wave & 1) * 32;               // m-offset
    const int wnb = (wave >> 1) * 64;             // col base (0 or 64)
    const int lr = lane & 15;
    const int lkb = (lane >> 4) * 16;
    f32x4 acc[2][4] = {};
    const char* arow0 = Ab + (size_t)(wm + lr) * 1024 + lkb;
    const char* arow1 = Ab + (size_t)(wm + 16 + lr) * 1024 + lkb;
    stageB(0);
    #pragma unroll
    for (int ph = 0; ph < 2; ++ph) {
        __syncthreads();                          // stage(ph) complete
        #pragma unroll 4
        for (int kk = 0; kk < 8; ++kk) {
            int kg = ph * 512 + kk * 64;
            bf16x8 a0 = *(const bf16x8*)(arow0 + kg);
            bf16x8 a1 = *(const bf16x8*)(arow1 + kg);
            int kb = kk * 64 + lkb;
            #pragma unroll
            for (int nf = 0; nf < 4; ++nf) {
                int c = wnb + nf * 16 + lr;
                bf16x8 b = *(const bf16x8*)(Bs + c * 512 + (kb ^ ((c & 7) << 4)));
                acc[0][nf] = __builtin_amdgcn_mfma_f32_16x16x32_bf16(a0, b, acc[0][nf], 0, 0, 0);
                acc[1][nf] = __builtin_amdgcn_mfma_f32_16x16x32_bf16(a1, b, acc[1][nf], 0, 0, 0);
            }
        }
        if (ph == 0) {
            __syncthreads();                      // all reads of phase-0 B done
            stageB(1);
        }
    }
    const int orow = (lane >> 4) * 4;
    float bcol[4];
    #pragma unroll
    for (int nf = 0; nf < 4; ++nf) bcol[nf] = bias[wnb + nf * 16 + lr];
    #pragma unroll
    for (int nf = 0; nf < 4; ++nf) {
        float cs = 0.f, cq = 0.f;
        int c = wnb + nf * 16 + lr;
        #pragma unroll
        for (int mi = 0; mi < 2; ++mi) {
            #pragma unroll
            for (int r = 0; r < 4; ++r) {
                int gr = m0 + wm + mi * 16 + orow + r;
                if (gr < M) {
                    float v = acc[mi][nf][r] + bcol[nf];
                    outb[(size_t)gr * DF + c] = __float2bfloat16(v);
                    cs += v; cq += v * v;
                }
            }
        }
        atomicAdd(&ssum[c], cs);
        atomicAdd(&ssq[c], cq);
    }
    __syncthreads();
    if (tid < 128) {
        atomicAdd(&stats[tid], ssum[tid]);
        atomicAdd(&stats[128 + tid], ssq[tid]);
    }
}

// ---------- BatchNorm apply (bf16 input, 8 elems/thread) ----------
__device__ __forceinline__ void bn_core(const uint4 v, int c0, const float* stats,
                                        const float* gamma, const float* beta, float* o) {
    float xv[8];
    xv[0] = __uint_as_float(v.x << 16); xv[1] = __uint_as_float(v.x & 0xffff0000u);
    xv[2] = __uint_as_float(v.y << 16); xv[3] = __uint_as_float(v.y & 0xffff0000u);
    xv[4] = __uint_as_float(v.z << 16); xv[5] = __uint_as_float(v.z & 0xffff0000u);
    xv[6] = __uint_as_float(v.w << 16); xv[7] = __uint_as_float(v.w & 0xffff0000u);
    #pragma unroll
    for (int k = 0; k < 8; ++k) {
        int c = c0 + k;
        float mu = stats[c] * (1.f / NN);
        float var = stats[128 + c] * (1.f / NN) - mu * mu;
        o[k] = fmaxf((xv[k] - mu) * rsqrtf(var + BN_EPS) * gamma[c] + beta[c], 0.f);
    }
}

__global__ __launch_bounds__(256) void bn_apply_bf16(const bf16* __restrict__ x, const float* __restrict__ stats,
                                                     const float* __restrict__ gamma, const float* __restrict__ beta,
                                                     bf16* __restrict__ out) {
    int i = blockIdx.x * 256 + threadIdx.x;
    if (i >= NN * DF / 8) return;
    uint4 v = reinterpret_cast<const uint4*>(x)[i];
    float o[8];
    bn_core(v, (i * 8) & 127, stats, gamma, beta, o);
    uint4 w;
    unsigned short* wb = reinterpret_cast<unsigned short*>(&w);
    #pragma unroll
    for (int k = 0; k < 8; ++k) {
        union { bf16 b; unsigned short u; } t;
        t.b = __float2bfloat16(o[k]);
        wb[k] = t.u;
    }
    reinterpret_cast<uint4*>(out)[i] = w;
}

__global__ __launch_bounds__(256) void bn_apply_f32(const bf16* __restrict__ x, const float* __restrict__ stats,
                                                    const float* __restrict__ gamma, const float* __restrict__ beta,
                                                    float* __restrict__ out) {
    int i = blockIdx.x * 256 + threadIdx.x;
    if (i >= NN * DF / 8) return;
    uint4 v = reinterpret_cast<const uint4*>(x)[i];
    float o[8];
    bn_core(v, (i * 8) & 127, stats, gamma, beta, o);
    float4* op = reinterpret_cast<float4*>(out) + (size_t)i * 2;
    op[0] = make_float4(o[0], o[1], o[2], o[3]);
    op[1] = make_float4(o[4], o[5], o[6], o[7]);
}

extern "C" void kernel_launch(void* const* d_in, const int* in_sizes, int n_in,
                              void* d_out, int out_size, void* d_ws, size_t ws_size,
                              hipStream_t stream) {
    (void)in_sizes; (void)n_in; (void)out_size; (void)ws_size;
    const float* x   = (const float*)d_in[0];
    const int*   ei  = (const int*)d_in[1];
    const float* W1  = (const float*)d_in[2];
    const float* as1 = (const float*)d_in[3];
    const float* ad1 = (const float*)d_in[4];
    const float* b1  = (const float*)d_in[5];
    const float* g1  = (const float*)d_in[6];
    const float* be1 = (const float*)d_in[7];
    const float* W2  = (const float*)d_in[8];
    const float* as2 = (const float*)d_in[9];
    const float* ad2 = (const float*)d_in[10];
    const float* b2  = (const float*)d_in[11];
    const float* g2  = (const float*)d_in[12];
    const float* be2 = (const float*)d_in[13];
    float* out = (float*)d_out;

    char* ws = (char*)d_ws;
    size_t off = 0;
    auto alloc = [&](size_t bytes) -> void* {
        void* p = ws + off;
        off += (bytes + 255) & ~(size_t)255;
        return p;
    };
    bf16*   aggX    = (bf16*)alloc((size_t)NP * HD * 2);      // 51.25 MB
    bf16*   xb      = (bf16*)alloc((size_t)NP * DF * 2);      // 12.8 MB (padded)
    bf16*   Bt2a    = (bf16*)alloc((size_t)DF * HD * 2);      // 128 KB
    bf16*   Bt2b    = (bf16*)alloc((size_t)DF * HD * 2);
    float*  wsd     = (float*)alloc(2 * 1024 * 4);            // 8 KB
    float*  a_src   = (float*)alloc((size_t)NN * NH * 4);
    float*  a_dst   = (float*)alloc((size_t)NN * NH * 4);
    int*    row_ptr = (int*)alloc((size_t)(NN + 1) * 4);
    int*    bsum    = (int*)alloc(256 * 4);
    int*    colidx  = (int*)alloc((size_t)ET * 4);
    bf16*   agg     = (bf16*)alloc((size_t)NN * DF * 2);      // 12.8 MB
    float*  stats   = (float*)alloc(256 * 4);
    // counts (padded 64B/dst, 3.2MB) + rank (3.4MB) aliased into agg (12.8MB;
    // agg first written by gemm_out, long after CSR build completes)
    int*    counts  = (int*)agg;
    int*    rank    = (int*)((char*)agg + ((size_t)NP << 6));
    // high-water ~82 MB (<= R1-proven 107.4 MB)

    const int NB = (NN + 255) / 256;        // 196
    const int EB2 = (ET / 2 + 255) / 256;   // 1661
    const int BNB = (NN * DF / 8 + 255) / 256;  // 3125

    // ---- prep + CSR build (single atomic pass) ----
    cvt_x_bf16<<<(NN * DF / 4 + 255) / 256, 256, 0, stream>>>(x, xb);
    make_wsd<<<8, 256, 0, stream>>>(W1, as1, ad1, W2, as2, ad2, wsd);
    cvt_bt2<<<(2 * DF * HD + 255) / 256, 256, 0, stream>>>(W1, W2, Bt2a, Bt2b);
    hipMemsetAsync(counts, 0, (size_t)NP << 6, stream);
    count_rank<<<EB2, 256, 0, stream>>>(ei, counts, rank);
    scan1<<<NB, 256, 0, stream>>>(counts, bsum);
    scan2<<<1, 256, 0, stream>>>(bsum, NB);
    scan3<<<NB, 256, 0, stream>>>(counts, bsum, row_ptr);
    fill_scatter<<<EB2, 256, 0, stream>>>(ei, rank, row_ptr, colidx);

    // ---- layer 1 ----
    xscore<<<NN / 4, 256, 0, stream>>>(xb, wsd, a_src, a_dst, stats);
    agg_fused<<<NN / 4, 256, 0, stream>>>(xb, a_src, a_dst, row_ptr, colidx, aggX);
    gemm_out<<<NP / 64, 256, 0, stream>>>(aggX, Bt2a, b1, agg, stats, NN);
    bn_apply_bf16<<<BNB, 256, 0, stream>>>(agg, stats, g1, be1, xb);

    // ---- layer 2 ----
    xscore<<<NN / 4, 256, 0, stream>>>(xb, wsd + 1024, a_src, a_dst, stats);
    agg_fused<<<NN / 4, 256, 0, stream>>>(xb, a_src, a_dst, row_ptr, colidx, aggX);
    gemm_out<<<NP / 64, 256, 0, stream>>>(aggX, Bt2b, b2, agg, stats, NN);
    bn_apply_f32<<<BNB, 256, 0, stream>>>(agg, stats, g2, be2, out);
}